// Round 7
// baseline (1524.621 us; speedup 1.0000x reference)
//
#include <hip/hip_runtime.h>

// ---------------------------------------------------------------------------
// DVGMamba forward. Round 7: 78 -> 53 launches.
//  - single-kernel chunked scan (in-block chunk prefix, no global pairs)
//  - out_proj/fc2 GEMMs carry addnorm epilogue via last-block counters
//    (no spin-waiting -- round-5 lesson: chained cross-XCD waits are poison)
//  - tokenize does layer-0 addnorm; fc2(L7) epilogue uses norm_f; head does loss
// b=2, l=64, S=256 tokens, D=512, DIN=1024, DS=16, DTR=32, K=4, Layers=8
// ---------------------------------------------------------------------------

#define SEQ  256

typedef __attribute__((ext_vector_type(8))) short bf16x8;
typedef __attribute__((ext_vector_type(16))) float f32x16;

__device__ __forceinline__ float silu_f(float x) { return x / (1.0f + expf(-x)); }
__device__ __forceinline__ float softplus_f(float x) {
  return (x > 20.0f) ? x : log1pf(expf(x));
}

// split fp32 -> (hi bf16, lo bf16) by truncation; packed 2x bf16 per dword
__device__ __forceinline__ void split_pack(float4 v, uint2* hi, uint2* lo) {
  uint ux = __float_as_uint(v.x), uy = __float_as_uint(v.y);
  uint uz = __float_as_uint(v.z), uw = __float_as_uint(v.w);
  hi->x = (ux >> 16) | (uy & 0xffff0000u);
  hi->y = (uz >> 16) | (uw & 0xffff0000u);
  float lx = v.x - __uint_as_float(ux & 0xffff0000u);
  float ly = v.y - __uint_as_float(uy & 0xffff0000u);
  float lz = v.z - __uint_as_float(uz & 0xffff0000u);
  float lw = v.w - __uint_as_float(uw & 0xffff0000u);
  lo->x = (__float_as_uint(lx) >> 16) | (__float_as_uint(ly) & 0xffff0000u);
  lo->y = (__float_as_uint(lz) >> 16) | (__float_as_uint(lw) & 0xffff0000u);
}

// --------------------------- split-bf16 MFMA NT GEMM (plain) ---------------
__global__ __launch_bounds__(256) void gemm_bs_k(const float* __restrict__ A,
                                                 const float* __restrict__ B,
                                                 float* __restrict__ C,
                                                 int M, int N, int K, int Kc) {
  __shared__ alignas(16) ushort sAh[2][2][512];
  __shared__ alignas(16) ushort sAl[2][2][512];
  __shared__ alignas(16) ushort sBh[2][2][512];
  __shared__ alignas(16) ushort sBl[2][2][512];
  int t = threadIdx.x;
  int bn = blockIdx.x, bm = blockIdx.y, z = blockIdx.z;
  const float* Ab = A + (size_t)bm * 64 * K + (size_t)z * Kc;
  const float* Bb = B + (size_t)bn * 64 * K + (size_t)z * Kc;
  float* Cb = C + (size_t)z * M * N;
  int r = t >> 2, kc = (t & 3) << 2;
  int st = r >> 5, m = r & 31;
  int off = ((kc >> 3) << 8) + (m << 3) + (kc & 7);
  int w = t >> 6, lane = t & 63;
  int wr = w >> 1, wc = w & 1;

  f32x16 acc;
#pragma unroll
  for (int i = 0; i < 16; ++i) acc[i] = 0.f;

  int nk = Kc >> 4;
  float4 a4 = *(const float4*)&Ab[(size_t)r * K + kc];
  float4 b4 = *(const float4*)&Bb[(size_t)r * K + kc];
  {
    uint2 hi, lo;
    split_pack(a4, &hi, &lo);
    *(uint2*)&sAh[0][st][off] = hi; *(uint2*)&sAl[0][st][off] = lo;
    split_pack(b4, &hi, &lo);
    *(uint2*)&sBh[0][st][off] = hi; *(uint2*)&sBl[0][st][off] = lo;
  }
  __syncthreads();
  for (int ks = 0; ks < nk; ++ks) {
    int buf = ks & 1;
    if (ks + 1 < nk) {
      a4 = *(const float4*)&Ab[(size_t)r * K + (ks + 1) * 16 + kc];
      b4 = *(const float4*)&Bb[(size_t)r * K + (ks + 1) * 16 + kc];
    }
    bf16x8 ah = *(bf16x8*)&sAh[buf][wr][lane << 3];
    bf16x8 al = *(bf16x8*)&sAl[buf][wr][lane << 3];
    bf16x8 bh = *(bf16x8*)&sBh[buf][wc][lane << 3];
    bf16x8 bl = *(bf16x8*)&sBl[buf][wc][lane << 3];
    acc = __builtin_amdgcn_mfma_f32_32x32x16_bf16(ah, bh, acc, 0, 0, 0);
    acc = __builtin_amdgcn_mfma_f32_32x32x16_bf16(al, bh, acc, 0, 0, 0);
    acc = __builtin_amdgcn_mfma_f32_32x32x16_bf16(ah, bl, acc, 0, 0, 0);
    if (ks + 1 < nk) {
      uint2 hi, lo;
      split_pack(a4, &hi, &lo);
      *(uint2*)&sAh[buf ^ 1][st][off] = hi; *(uint2*)&sAl[buf ^ 1][st][off] = lo;
      split_pack(b4, &hi, &lo);
      *(uint2*)&sBh[buf ^ 1][st][off] = hi; *(uint2*)&sBl[buf ^ 1][st][off] = lo;
    }
    __syncthreads();
  }
  int col = lane & 31, rq = lane >> 5;
  float* Cw = Cb + (size_t)(bm * 64 + wr * 32) * N + bn * 64 + wc * 32 + col;
#pragma unroll
  for (int rg = 0; rg < 16; ++rg) {
    int row = (rg & 3) + ((rg >> 2) << 3) + (rq << 2);
    Cw[(size_t)row * N] = acc[rg];
  }
}

// --------------------------- addnorm epilogue helper -----------------------
// Last-arriving block of row-group bm sums 4 partials into residual, rmsnorms,
// writes xn. Wave w handles 16 rows; 64 lanes cover 512 cols (8 each).
__device__ __forceinline__ void addnorm_epilogue(int bm, const float* __restrict__ P,
                                                 float* __restrict__ res,
                                                 const float* __restrict__ nw,
                                                 float* __restrict__ xn) {
  int w = threadIdx.x >> 6, lane = threadIdx.x & 63;
  int c0 = lane * 8;
  float4 w0 = *(const float4*)&nw[c0];
  float4 w1 = *(const float4*)&nw[c0 + 4];
#pragma unroll 1
  for (int i = 0; i < 16; ++i) {
    int R = bm * 64 + w * 16 + i;
    float4 r0 = *(float4*)&res[(size_t)R * 512 + c0];
    float4 r1 = *(float4*)&res[(size_t)R * 512 + c0 + 4];
#pragma unroll
    for (int p = 0; p < 4; ++p) {
      const float* pp = P + (size_t)p * 262144 + (size_t)R * 512 + c0;
      float4 v0 = *(const float4*)&pp[0];
      float4 v1 = *(const float4*)&pp[4];
      r0.x += v0.x; r0.y += v0.y; r0.z += v0.z; r0.w += v0.w;
      r1.x += v1.x; r1.y += v1.y; r1.z += v1.z; r1.w += v1.w;
    }
    *(float4*)&res[(size_t)R * 512 + c0] = r0;
    *(float4*)&res[(size_t)R * 512 + c0 + 4] = r1;
    float ss = r0.x * r0.x + r0.y * r0.y + r0.z * r0.z + r0.w * r0.w +
               r1.x * r1.x + r1.y * r1.y + r1.z * r1.z + r1.w * r1.w;
    for (int o = 1; o < 64; o <<= 1) ss += __shfl_xor(ss, o, 64);
    float sc = rsqrtf(ss * (1.0f / 512.0f) + 1e-5f);
    float4 o0 = {r0.x * sc * w0.x, r0.y * sc * w0.y, r0.z * sc * w0.z, r0.w * sc * w0.w};
    float4 o1 = {r1.x * sc * w1.x, r1.y * sc * w1.y, r1.z * sc * w1.z, r1.w * sc * w1.w};
    *(float4*)&xn[(size_t)R * 512 + c0] = o0;
    *(float4*)&xn[(size_t)R * 512 + c0 + 4] = o1;
  }
}

// --------------------------- GEMM + addnorm epilogue (plain A) -------------
__global__ __launch_bounds__(256) void gemm_ep_k(const float* __restrict__ A,
                                                 const float* __restrict__ B,
                                                 float* __restrict__ P,
                                                 float* __restrict__ res,
                                                 const float* __restrict__ nw,
                                                 float* __restrict__ xn,
                                                 int* __restrict__ cnt,
                                                 int M, int N, int K, int Kc) {
  __shared__ alignas(16) ushort sAh[2][2][512];
  __shared__ alignas(16) ushort sAl[2][2][512];
  __shared__ alignas(16) ushort sBh[2][2][512];
  __shared__ alignas(16) ushort sBl[2][2][512];
  __shared__ int sLast;
  int t = threadIdx.x;
  int bn = blockIdx.x, bm = blockIdx.y, z = blockIdx.z;
  const float* Ab = A + (size_t)bm * 64 * K + (size_t)z * Kc;
  const float* Bb = B + (size_t)bn * 64 * K + (size_t)z * Kc;
  float* Cb = P + (size_t)z * M * N;
  int r = t >> 2, kc = (t & 3) << 2;
  int st = r >> 5, m = r & 31;
  int off = ((kc >> 3) << 8) + (m << 3) + (kc & 7);
  int w = t >> 6, lane = t & 63;
  int wr = w >> 1, wc = w & 1;

  f32x16 acc;
#pragma unroll
  for (int i = 0; i < 16; ++i) acc[i] = 0.f;

  int nk = Kc >> 4;
  float4 a4 = *(const float4*)&Ab[(size_t)r * K + kc];
  float4 b4 = *(const float4*)&Bb[(size_t)r * K + kc];
  {
    uint2 hi, lo;
    split_pack(a4, &hi, &lo);
    *(uint2*)&sAh[0][st][off] = hi; *(uint2*)&sAl[0][st][off] = lo;
    split_pack(b4, &hi, &lo);
    *(uint2*)&sBh[0][st][off] = hi; *(uint2*)&sBl[0][st][off] = lo;
  }
  __syncthreads();
  for (int ks = 0; ks < nk; ++ks) {
    int buf = ks & 1;
    if (ks + 1 < nk) {
      a4 = *(const float4*)&Ab[(size_t)r * K + (ks + 1) * 16 + kc];
      b4 = *(const float4*)&Bb[(size_t)r * K + (ks + 1) * 16 + kc];
    }
    bf16x8 ah = *(bf16x8*)&sAh[buf][wr][lane << 3];
    bf16x8 al = *(bf16x8*)&sAl[buf][wr][lane << 3];
    bf16x8 bh = *(bf16x8*)&sBh[buf][wc][lane << 3];
    bf16x8 bl = *(bf16x8*)&sBl[buf][wc][lane << 3];
    acc = __builtin_amdgcn_mfma_f32_32x32x16_bf16(ah, bh, acc, 0, 0, 0);
    acc = __builtin_amdgcn_mfma_f32_32x32x16_bf16(al, bh, acc, 0, 0, 0);
    acc = __builtin_amdgcn_mfma_f32_32x32x16_bf16(ah, bl, acc, 0, 0, 0);
    if (ks + 1 < nk) {
      uint2 hi, lo;
      split_pack(a4, &hi, &lo);
      *(uint2*)&sAh[buf ^ 1][st][off] = hi; *(uint2*)&sAl[buf ^ 1][st][off] = lo;
      split_pack(b4, &hi, &lo);
      *(uint2*)&sBh[buf ^ 1][st][off] = hi; *(uint2*)&sBl[buf ^ 1][st][off] = lo;
    }
    __syncthreads();
  }
  int col = lane & 31, rq = lane >> 5;
  float* Cw = Cb + (size_t)(bm * 64 + wr * 32) * N + bn * 64 + wc * 32 + col;
#pragma unroll
  for (int rg = 0; rg < 16; ++rg) {
    int row = (rg & 3) + ((rg >> 2) << 3) + (rq << 2);
    Cw[(size_t)row * N] = acc[rg];
  }
  // ---- last-block addnorm epilogue (no waiting; loser blocks exit) ----
  __syncthreads();              // drains vmem before barrier -> stores visible
  if (t == 0) {
    int old = __hip_atomic_fetch_add(&cnt[bm], 1, __ATOMIC_ACQ_REL,
                                     __HIP_MEMORY_SCOPE_AGENT);
    sLast = (old == gridDim.x * gridDim.z - 1) ? 1 : 0;
  }
  __syncthreads();
  if (!sLast) return;
  addnorm_epilogue(bm, P, res, nw, xn);
}

// --------------------------- GEMM + GLU-A + addnorm epilogue ---------------
// A_logical[r,k] = g[r*2048+k] * silu(g[r*2048+1024+k]); K = 1024.
__global__ __launch_bounds__(256) void gemm_glu_ep_k(const float* __restrict__ G,
                                                     const float* __restrict__ B,
                                                     float* __restrict__ P,
                                                     float* __restrict__ res,
                                                     const float* __restrict__ nw,
                                                     float* __restrict__ xn,
                                                     int* __restrict__ cnt,
                                                     int M, int N, int K, int Kc) {
  __shared__ alignas(16) ushort sAh[2][2][512];
  __shared__ alignas(16) ushort sAl[2][2][512];
  __shared__ alignas(16) ushort sBh[2][2][512];
  __shared__ alignas(16) ushort sBl[2][2][512];
  __shared__ int sLast;
  int t = threadIdx.x;
  int bn = blockIdx.x, bm = blockIdx.y, z = blockIdx.z;
  const float* Gb = G + (size_t)bm * 64 * 2048 + (size_t)z * Kc;
  const float* Bb = B + (size_t)bn * 64 * K + (size_t)z * Kc;
  float* Cb = P + (size_t)z * M * N;
  int r = t >> 2, kc = (t & 3) << 2;
  int st = r >> 5, m = r & 31;
  int off = ((kc >> 3) << 8) + (m << 3) + (kc & 7);
  int w = t >> 6, lane = t & 63;
  int wr = w >> 1, wc = w & 1;

  f32x16 acc;
#pragma unroll
  for (int i = 0; i < 16; ++i) acc[i] = 0.f;

  int nk = Kc >> 4;
  const float* gr = Gb + (size_t)r * 2048 + kc;
  float4 ga = *(const float4*)&gr[0];
  float4 gz = *(const float4*)&gr[1024];
  float4 b4 = *(const float4*)&Bb[(size_t)r * K + kc];
  {
    float4 a4 = {ga.x * silu_f(gz.x), ga.y * silu_f(gz.y),
                 ga.z * silu_f(gz.z), ga.w * silu_f(gz.w)};
    uint2 hi, lo;
    split_pack(a4, &hi, &lo);
    *(uint2*)&sAh[0][st][off] = hi; *(uint2*)&sAl[0][st][off] = lo;
    split_pack(b4, &hi, &lo);
    *(uint2*)&sBh[0][st][off] = hi; *(uint2*)&sBl[0][st][off] = lo;
  }
  __syncthreads();
  for (int ks = 0; ks < nk; ++ks) {
    int buf = ks & 1;
    if (ks + 1 < nk) {
      ga = *(const float4*)&gr[(ks + 1) * 16];
      gz = *(const float4*)&gr[1024 + (ks + 1) * 16];
      b4 = *(const float4*)&Bb[(size_t)r * K + (ks + 1) * 16 + kc];
    }
    bf16x8 ah = *(bf16x8*)&sAh[buf][wr][lane << 3];
    bf16x8 al = *(bf16x8*)&sAl[buf][wr][lane << 3];
    bf16x8 bh = *(bf16x8*)&sBh[buf][wc][lane << 3];
    bf16x8 bl = *(bf16x8*)&sBl[buf][wc][lane << 3];
    acc = __builtin_amdgcn_mfma_f32_32x32x16_bf16(ah, bh, acc, 0, 0, 0);
    acc = __builtin_amdgcn_mfma_f32_32x32x16_bf16(al, bh, acc, 0, 0, 0);
    acc = __builtin_amdgcn_mfma_f32_32x32x16_bf16(ah, bl, acc, 0, 0, 0);
    if (ks + 1 < nk) {
      float4 a4 = {ga.x * silu_f(gz.x), ga.y * silu_f(gz.y),
                   ga.z * silu_f(gz.z), ga.w * silu_f(gz.w)};
      uint2 hi, lo;
      split_pack(a4, &hi, &lo);
      *(uint2*)&sAh[buf ^ 1][st][off] = hi; *(uint2*)&sAl[buf ^ 1][st][off] = lo;
      split_pack(b4, &hi, &lo);
      *(uint2*)&sBh[buf ^ 1][st][off] = hi; *(uint2*)&sBl[buf ^ 1][st][off] = lo;
    }
    __syncthreads();
  }
  int col = lane & 31, rq = lane >> 5;
  float* Cw = Cb + (size_t)(bm * 64 + wr * 32) * N + bn * 64 + wc * 32 + col;
#pragma unroll
  for (int rg = 0; rg < 16; ++rg) {
    int row = (rg & 3) + ((rg >> 2) << 3) + (rq << 2);
    Cw[(size_t)row * N] = acc[rg];
  }
  __syncthreads();
  if (t == 0) {
    int old = __hip_atomic_fetch_add(&cnt[bm], 1, __ATOMIC_ACQ_REL,
                                     __HIP_MEMORY_SCOPE_AGENT);
    sLast = (old == gridDim.x * gridDim.z - 1) ? 1 : 0;
  }
  __syncthreads();
  if (!sLast) return;
  addnorm_epilogue(bm, P, res, nw, xn);
}

// --------------------------- patch mean, two stage -------------------------
// stage 1 also zeroes the epilogue counters (block 0).
__global__ void patch_part_k(const float* __restrict__ img, float* __restrict__ pmp,
                             int* __restrict__ cnt) {
  int blk = blockIdx.x;
  int t = threadIdx.x;
  if (blk == 0 && t < 136) cnt[t] = 0;
  int bl = blk / 14, hb = blk % 14;
  int c = t >> 6, hi = (t >> 2) & 15, wi4 = t & 3;
  const float* base = img + (size_t)bl * 3 * 50176 + (size_t)c * 50176 +
                      (size_t)(hb * 16 + hi) * 224 + wi4 * 4;
  float4 s = {0.f, 0.f, 0.f, 0.f};
#pragma unroll
  for (int wb = 0; wb < 14; ++wb) {
    float4 v = *(const float4*)&base[wb * 16];
    s.x += v.x; s.y += v.y; s.z += v.z; s.w += v.w;
  }
  ((float4*)(pmp + (size_t)blk * 768))[t] = s;
}

__global__ void patch_red_k(const float* __restrict__ pmp, float* __restrict__ meanp) {
  int bl = blockIdx.x;
  int t = threadIdx.x;
  float4 s = {0.f, 0.f, 0.f, 0.f};
  for (int hb = 0; hb < 14; ++hb) {
    float4 v = ((const float4*)(pmp + (size_t)(bl * 14 + hb) * 768))[t];
    s.x += v.x; s.y += v.y; s.z += v.z; s.w += v.w;
  }
  const float inv = 1.0f / 196.0f;
  float4 o = {s.x * inv, s.y * inv, s.z * inv, s.w * inv};
  ((float4*)(meanp + (size_t)bl * 768))[t] = o;
}

// --------------------------- tokenize + layer-0 addnorm --------------------
__global__ void tokenize_k(const float* __restrict__ imgp,
                           const float* __restrict__ states,
                           const float* __restrict__ actions,
                           const float* __restrict__ pb,
                           const float* __restrict__ sw, const float* __restrict__ sb,
                           const float* __restrict__ aw, const float* __restrict__ ab,
                           const float* __restrict__ n1w,
                           float* __restrict__ residual, float* __restrict__ xn) {
  int tok = blockIdx.x;
  int t = threadIdx.x;
  int j = tok & 3;
  int bl = tok >> 2;
  int o0 = t * 4;
  float out[4];
  if (j == 0) {
    float4 a = ((const float4*)pb)[t];
    const float* ip = imgp + (size_t)bl * 512;
#pragma unroll
    for (int p = 0; p < 8; ++p) {
      float4 v = ((const float4*)(ip + (size_t)p * 65536))[t];
      a.x += v.x; a.y += v.y; a.z += v.z; a.w += v.w;
    }
    out[0] = a.x; out[1] = a.y; out[2] = a.z; out[3] = a.w;
  } else if (j == 1) {
    const float* sv = states + (size_t)bl * 21;
#pragma unroll
    for (int i = 0; i < 4; ++i) {
      int o = o0 + i;
      float acc = sb[o];
      for (int k = 0; k < 7; ++k) acc += sw[o * 7 + k] * sv[k];
      out[i] = acc;
    }
  } else {
    const float* av = actions + ((size_t)bl * 3 + (j - 2)) * 4;
#pragma unroll
    for (int i = 0; i < 4; ++i) {
      int o = o0 + i;
      float acc = ab[o];
      for (int k = 0; k < 4; ++k) acc += aw[o * 4 + k] * av[k];
      out[i] = acc;
    }
  }
  float4 ov = {out[0], out[1], out[2], out[3]};
  ((float4*)(residual + (size_t)tok * 512))[t] = ov;
  float ss = ov.x * ov.x + ov.y * ov.y + ov.z * ov.z + ov.w * ov.w;
  for (int off = 32; off; off >>= 1) ss += __shfl_down(ss, off, 64);
  __shared__ float s2[2];
  if ((t & 63) == 0) s2[t >> 6] = ss;
  __syncthreads();
  float tot = s2[0] + s2[1];
  float scale = rsqrtf(tot * (1.0f / 512.0f) + 1e-5f);
  float4 wv = ((const float4*)n1w)[t];
  float4 o = {ov.x * scale * wv.x, ov.y * scale * wv.y,
              ov.z * scale * wv.z, ov.w * scale * wv.w};
  ((float4*)(xn + (size_t)tok * 512))[t] = o;
}

// --------------------------- fused conv+silu+xproj+dt ----------------------
__global__ __launch_bounds__(256) void convproj_k(const float* __restrict__ xz,
                                                  const float* __restrict__ cw,
                                                  const float* __restrict__ cb,
                                                  const float* __restrict__ xpw,
                                                  const float* __restrict__ dtw,
                                                  const float* __restrict__ dtbias,
                                                  float* __restrict__ xc,
                                                  float* __restrict__ proj,
                                                  float* __restrict__ dt) {
  int tok = blockIdx.x;
  int t = threadIdx.x;
  int b = tok >> 8, s = tok & 255;
  __shared__ float xr[1024];
  __shared__ float pp[4][64];
  __shared__ float pr[64];
  int d4 = t * 4;
  float4 cw0 = ((const float4*)cw)[d4];
  float4 cw1 = ((const float4*)cw)[d4 + 1];
  float4 cw2 = ((const float4*)cw)[d4 + 2];
  float4 cw3 = ((const float4*)cw)[d4 + 3];
  float acc0 = cb[d4], acc1 = cb[d4 + 1], acc2 = cb[d4 + 2], acc3 = cb[d4 + 3];
  const float* base = xz + (size_t)b * 256 * 2048 + d4;
  const float wk0[4] = {cw0.x, cw0.y, cw0.z, cw0.w};
  const float wk1[4] = {cw1.x, cw1.y, cw1.z, cw1.w};
  const float wk2[4] = {cw2.x, cw2.y, cw2.z, cw2.w};
  const float wk3[4] = {cw3.x, cw3.y, cw3.z, cw3.w};
#pragma unroll
  for (int k = 0; k < 4; ++k) {
    int row = s + k - 3;
    if (row >= 0) {
      float4 v = *(const float4*)&base[(size_t)row * 2048];
      acc0 += wk0[k] * v.x; acc1 += wk1[k] * v.y;
      acc2 += wk2[k] * v.z; acc3 += wk3[k] * v.w;
    }
  }
  float4 xc4 = {silu_f(acc0), silu_f(acc1), silu_f(acc2), silu_f(acc3)};
  ((float4*)(xc + (size_t)tok * 1024))[t] = xc4;
  *(float4*)&xr[d4] = xc4;
  __syncthreads();
  int n = t & 63, q = t >> 6;
  {
    const float* wrow = xpw + (size_t)n * 1024 + q * 256;
    const float* xq = xr + q * 256;
    float acc = 0.f;
    for (int k = 0; k < 256; k += 4)
      acc += wrow[k] * xq[k] + wrow[k + 1] * xq[k + 1] +
             wrow[k + 2] * xq[k + 2] + wrow[k + 3] * xq[k + 3];
    pp[q][n] = acc;
  }
  __syncthreads();
  if (t < 64) {
    float v = pp[0][t] + pp[1][t] + pp[2][t] + pp[3][t];
    pr[t] = v;
    proj[(size_t)tok * 64 + t] = v;
  }
  __syncthreads();
#pragma unroll
  for (int i = 0; i < 4; ++i) {
    int d = t * 4 + i;
    const float* dw = dtw + (size_t)d * 32;
    float a = dtbias[d];
    for (int k = 0; k < 32; ++k) a += dw[k] * pr[k];
    dt[(size_t)tok * 1024 + d] = softplus_f(a);
  }
}

// --------------------------- single-kernel chunked scan --------------------
// 512 blocks = b(2) x dgroup(256, 4 d's). 256 thr = 4 chunk-slots x 64 lanes
// (lane = dl*16+n). Pass1: chunk pairs -> in-block 8-step prefix -> pass2.
__global__ __launch_bounds__(256) void scan_k(const float* __restrict__ dt,
                                              const float* __restrict__ proj,
                                              const float* __restrict__ xc,
                                              const float* __restrict__ xz,
                                              const float* __restrict__ alog,
                                              const float* __restrict__ Dp,
                                              float* __restrict__ yz) {
  __shared__ float sDt[256][4];
  __shared__ float sXc[256][4];
  __shared__ float sZ[256][4];
  __shared__ float sBC[256][32];
  __shared__ float2 sPair[8][64];
  __shared__ float sH0[8][64];
  __shared__ float sY[256][4];
  int tid = threadIdx.x;
  int b = blockIdx.x >> 8;
  int d0 = (blockIdx.x & 255) << 2;
  int cs = tid >> 6, lane = tid & 63;
  int dl = lane >> 4, n = lane & 15;
  int d = d0 + dl;
  float A = -expf(alog[d * 16 + n]);
  float dp = Dp[d];
  // stage full sequence for 4 d's + B/C
  {
    const float* dtp = dt + ((size_t)b * 256 + tid) * 1024 + d0;
    const float* xcp = xc + ((size_t)b * 256 + tid) * 1024 + d0;
    const float* zp  = xz + ((size_t)b * 256 + tid) * 2048 + 1024 + d0;
    *(float4*)&sDt[tid][0] = *(const float4*)dtp;
    *(float4*)&sXc[tid][0] = *(const float4*)xcp;
    *(float4*)&sZ[tid][0]  = *(const float4*)zp;
#pragma unroll
    for (int j = 0; j < 8; ++j) {
      int idx = tid + j * 256;
      int row = idx >> 3, f4 = (idx & 7) * 4;
      *(float4*)&sBC[row][f4] =
          *(const float4*)&proj[((size_t)b * 256 + row) * 64 + 32 + f4];
    }
  }
  __syncthreads();
  // pass 1: chunk pairs for chunks cs and cs+4
#pragma unroll
  for (int rr = 0; rr < 2; ++rr) {
    int c = cs + rr * 4;
    float ap = 1.f, bc = 0.f;
#pragma unroll
    for (int i = 0; i < 32; ++i) {
      int s = c * 32 + i;
      float dtv = sDt[s][dl];
      float dA = __expf(dtv * A);
      bc = dA * bc + dtv * sBC[s][n] * sXc[s][dl];
      ap *= dA;
    }
    sPair[c][lane] = make_float2(ap, bc);
  }
  __syncthreads();
  // in-block exclusive prefix over 8 chunks (64 threads)
  if (tid < 64) {
    float h = 0.f;
#pragma unroll
    for (int c = 0; c < 8; ++c) {
      sH0[c][tid] = h;
      float2 p = sPair[c][tid];
      h = p.x * h + p.y;
    }
  }
  __syncthreads();
  // pass 2: re-walk with h0, gate, write y
#pragma unroll
  for (int rr = 0; rr < 2; ++rr) {
    int c = cs + rr * 4;
    float h = sH0[c][lane];
#pragma unroll
    for (int i = 0; i < 32; ++i) {
      int s = c * 32 + i;
      float dtv = sDt[s][dl];
      float xcv = sXc[s][dl];
      float dA = __expf(dtv * A);
      h = dA * h + dtv * sBC[s][n] * xcv;
      float yc = h * sBC[s][16 + n];
      yc += __shfl_xor(yc, 1, 64);
      yc += __shfl_xor(yc, 2, 64);
      yc += __shfl_xor(yc, 4, 64);
      yc += __shfl_xor(yc, 8, 64);
      if (n == 0) sY[s][dl] = (yc + dp * xcv) * silu_f(sZ[s][dl]);
    }
  }
  __syncthreads();
  *(float4*)&yz[((size_t)b * 256 + tid) * 1024 + d0] = *(float4*)&sY[tid][0];
}

// --------------------------- head + |diff| + loss (last block) -------------
__global__ void head_k(const float* __restrict__ hf, const float* __restrict__ hw,
                       const float* __restrict__ hb, const float* __restrict__ labels,
                       const int* __restrict__ seqlen, int* __restrict__ cnt,
                       float* __restrict__ preds, float* __restrict__ labs,
                       float* __restrict__ loss_out) {
  int blk = blockIdx.x;
  int j = blk % 3;
  int l = (blk / 3) % 64;
  int b = blk / 192;
  int row = b * 256 + l * 4 + 1 + j;
  int t = threadIdx.x;
  const float* x = hf + (size_t)row * 512;
  float acc[4] = {0.f, 0.f, 0.f, 0.f};
  for (int k = t; k < 512; k += 64) {
    float xv = x[k];
#pragma unroll
    for (int a = 0; a < 4; ++a) acc[a] += xv * hw[a * 512 + k];
  }
  for (int off = 32; off; off >>= 1) {
#pragma unroll
    for (int a = 0; a < 4; ++a) acc[a] += __shfl_down(acc[a], off, 64);
  }
  __shared__ int sLast;
  if (t == 0) {
    const float* lab = labels + (size_t)blk * 4;
    float sd = 0.f;
#pragma unroll
    for (int a = 0; a < 4; ++a) {
      float p = acc[a] + hb[a];
      preds[(size_t)blk * 4 + a] = p;
      sd += fabsf(p - lab[a]);
    }
    labs[blk] = sd;
    int old = __hip_atomic_fetch_add(&cnt[128], 1, __ATOMIC_ACQ_REL,
                                     __HIP_MEMORY_SCOPE_AGENT);
    sLast = (old == 383) ? 1 : 0;
  }
  __syncthreads();
  if (!sLast) return;
  // loss over all 384 labs (this block's 64 threads; t = l)
  float rb[2];
#pragma unroll
  for (int bb = 0; bb < 2; ++bb) {
    int base = (bb * 64 + t) * 3;
    float la = (labs[base] + labs[base + 1] + labs[base + 2]) * (1.0f / 12.0f);
    float m = (t < seqlen[bb]) ? 1.f : 0.f;
    float v = la * m;
    for (int off = 32; off; off >>= 1) {
      v += __shfl_down(v, off, 64);
      m += __shfl_down(m, off, 64);
    }
    rb[bb] = v / fmaxf(m, 1.0f);
  }
  if (t == 0) loss_out[0] = 0.5f * (rb[0] + rb[1]);
}

// ---------------------------------------------------------------------------
extern "C" void kernel_launch(void* const* d_in, const int* in_sizes, int n_in,
                              void* d_out, int out_size, void* d_ws, size_t ws_size,
                              hipStream_t stream) {
  const float* images     = (const float*)d_in[0];
  const int*   seq_length = (const int*)d_in[1];
  const float* states     = (const float*)d_in[2];
  const float* actions    = (const float*)d_in[3];
  const float* labels     = (const float*)d_in[4];
  const float* patch_w    = (const float*)d_in[5];
  const float* patch_b    = (const float*)d_in[6];
  const float* state_w    = (const float*)d_in[7];
  const float* state_b    = (const float*)d_in[8];
  const float* act_w      = (const float*)d_in[9];
  const float* act_b      = (const float*)d_in[10];
  const float* norm1_w    = (const float*)d_in[11];
  const float* in_proj_w  = (const float*)d_in[12];
  const float* conv_w     = (const float*)d_in[13];
  const float* conv_b     = (const float*)d_in[14];
  const float* x_proj_w   = (const float*)d_in[15];
  const float* dt_w       = (const float*)d_in[16];
  const float* dt_b       = (const float*)d_in[17];
  const float* A_log      = (const float*)d_in[18];
  const float* Dp         = (const float*)d_in[19];
  const float* out_proj_w = (const float*)d_in[20];
  const float* norm2_w    = (const float*)d_in[21];
  const float* fc1_w      = (const float*)d_in[22];
  const float* fc2_w      = (const float*)d_in[23];
  const float* norm_f_w   = (const float*)d_in[24];
  const float* head_w     = (const float*)d_in[25];
  const float* head_b     = (const float*)d_in[26];

  float* out = (float*)d_out;

  float* ws = (float*)d_ws;
  float* meanp    = ws; ws += 98304;     // (128, 768)
  float* residual = ws; ws += 262144;
  float* xn       = ws; ws += 262144;
  float* xz       = ws; ws += 1048576;   // (512, 2048)
  float* xc       = ws; ws += 524288;    // (512, 1024)
  float* proj     = ws; ws += 32768;     // (512, 64)
  float* dtbuf    = ws; ws += 524288;    // (512, 1024)
  float* yz       = ws; ws += 524288;    // (512, 1024)
  float* labs     = ws; ws += 384;
  float* cpart    = ws; ws += 1048576;   // partials (4x512x512 / 8x128x512)
  float* pmp      = ws; ws += 1376256;   // (1792, 768) patch partials
  int*   cnts     = (int*)ws; ws += 136; // 8 layers x 16 + head

  hipLaunchKernelGGL(patch_part_k, dim3(1792), dim3(192), 0, stream, images, pmp, cnts);
  hipLaunchKernelGGL(patch_red_k, dim3(128), dim3(192), 0, stream, pmp, meanp);
  hipLaunchKernelGGL(gemm_bs_k, dim3(8, 2, 8), dim3(256), 0, stream,
                     meanp, patch_w, cpart, 128, 512, 768, 96);
  hipLaunchKernelGGL(tokenize_k, dim3(512), dim3(128), 0, stream, cpart, states, actions,
                     patch_b, state_w, state_b, act_w, act_b, norm1_w, residual, xn);

  for (int i = 0; i < 8; ++i) {
    const float* ipw = in_proj_w + (size_t)i * 2048 * 512;
    const float* cw = conv_w + (size_t)i * 4096;
    const float* cb = conv_b + (size_t)i * 1024;
    const float* xpw = x_proj_w + (size_t)i * 65536;
    const float* dtw = dt_w + (size_t)i * 32768;
    const float* dtbias = dt_b + (size_t)i * 1024;
    const float* al = A_log + (size_t)i * 16384;
    const float* dpp = Dp + (size_t)i * 1024;
    const float* opw = out_proj_w + (size_t)i * 524288;
    const float* n2 = norm2_w + i * 512;
    const float* f1 = fc1_w + (size_t)i * 1048576;
    const float* f2 = fc2_w + (size_t)i * 524288;
    const float* nw_next = (i < 7) ? (norm1_w + (i + 1) * 512) : norm_f_w;

    hipLaunchKernelGGL(gemm_bs_k, dim3(32, 8, 1), dim3(256), 0, stream,
                       xn, ipw, xz, 512, 2048, 512, 512);
    hipLaunchKernelGGL(convproj_k, dim3(512), dim3(256), 0, stream,
                       xz, cw, cb, xpw, dtw, dtbias, xc, proj, dtbuf);
    hipLaunchKernelGGL(scan_k, dim3(512), dim3(256), 0, stream,
                       dtbuf, proj, xc, xz, al, dpp, yz);
    hipLaunchKernelGGL(gemm_ep_k, dim3(8, 8, 4), dim3(256), 0, stream,
                       yz, opw, cpart, residual, n2, xn, cnts + i * 16,
                       512, 512, 1024, 256);
    hipLaunchKernelGGL(gemm_bs_k, dim3(32, 8, 1), dim3(256), 0, stream,
                       xn, f1, xz, 512, 2048, 512, 512);
    hipLaunchKernelGGL(gemm_glu_ep_k, dim3(8, 8, 4), dim3(256), 0, stream,
                       xz, f2, cpart, residual, nw_next, xn, cnts + i * 16 + 8,
                       512, 512, 1024, 256);
  }

  hipLaunchKernelGGL(head_k, dim3(384), dim3(64), 0, stream, xn, head_w, head_b,
                     labels, seq_length, cnts, out + 1, labs, out);
}